// Round 3
// baseline (88.421 us; speedup 1.0000x reference)
//
#include <hip/hip_runtime.h>

// Problem constants (from reference setup_inputs / OUTPUT_LENGTH)
#define B_SZ 16
#define N_SZ 512
#define C_SZ 512
#define L_SZ 2048
#define ROW4 (C_SZ / 4)                      // 128 float4 per row
#define THREADS 256
#define ROWS_PER_BLK 8                       // 16 KB contiguous per block
#define BLKS_PER_BATCH (L_SZ / ROWS_PER_BLK) // 256
#define NBLOCKS (B_SZ * BLKS_PER_BATCH)      // 4096 -> 2 occupancy generations
#define NWAVES (THREADS / 64)                // 4

typedef float f32x4 __attribute__((ext_vector_type(4)));

// ---------------------------------------------------------------------------
// Fused kernel, round 3 shape:
//  - plain float4 stores (nt measured neutral in R2; match the 6.29 TB/s
//    copy pattern and the fill kernel),
//  - 4096 blocks x 8 rows: grid = 2x CU wave capacity, so blocks retire and
//    backfill (smooths copy-region vs zero-region imbalance),
//  - same cheap prologue: shfl-scan cumsum + LDS binary search.
// ---------------------------------------------------------------------------
__global__ __launch_bounds__(THREADS) void lenreg_fused_kernel(
    const float* __restrict__ enc,   // (B, N, C) fp32
    const float* __restrict__ ldur,  // (B, N, 1) fp32
    float* __restrict__ out)         // (B, L, C) fp32
{
    __shared__ int ends_s[N_SZ];        // inclusive cumsum of durations
    __shared__ int wtot[NWAVES];
    __shared__ int pl[ROWS_PER_BLK];    // phoneme index per row, -1 = zero

    const int tid  = threadIdx.x;
    const int lane = tid & 63;
    const int w    = tid >> 6;

    // XCD-contiguous swizzle (4096 % 8 == 0 -> bijective): each XCD owns
    // 512 consecutive blocks = 2 whole batches (2 MB enc working set).
    const int bid = blockIdx.x;
    const int swz = (bid & 7) * (NBLOCKS / 8) + (bid >> 3);
    const int b   = swz >> 8;                               // / BLKS_PER_BATCH
    const int l0  = (swz & (BLKS_PER_BATCH - 1)) * ROWS_PER_BLK;

    // ---- durations (reference math) + inclusive scan, 2 elems/thread ----
    const float2 ld2 = ((const float2*)(ldur + b * N_SZ))[tid];
    const int d0 = (ld2.x > 0.0f) ? (int)floorf(exp2f(ld2.x) + 1e-4f) : 0;
    const int d1 = (ld2.y > 0.0f) ? (int)floorf(exp2f(ld2.y) + 1e-4f) : 0;

    int scan = d0 + d1;                  // pair sum
    #pragma unroll
    for (int o = 1; o < 64; o <<= 1) {
        const int v = __shfl_up(scan, o, 64);
        if (lane >= o) scan += v;
    }
    if (lane == 63) wtot[w] = scan;
    __syncthreads();

    int base = 0;
    #pragma unroll
    for (int i = 0; i < NWAVES; ++i)
        if (i < w) base += wtot[i];

    const int e1 = base + scan;          // ends[2*tid+1]
    ends_s[2 * tid + 1] = e1;
    ends_s[2 * tid]     = e1 - d1;
    __syncthreads();

    // ---- per-row lower_bound: smallest i with ends[i] > l ----
    if (tid < ROWS_PER_BLK) {
        const int l = l0 + tid;
        int lo = 0, hi = N_SZ;
        #pragma unroll 1
        while (lo < hi) {                // 9 uniform iterations
            const int mid = (lo + hi) >> 1;
            if (ends_s[mid] > l) hi = mid; else lo = mid + 1;
        }
        pl[tid] = (lo < N_SZ) ? lo : -1;
    }
    __syncthreads();

    // ---- copy 8 rows x 512 floats; 4 independent float4 per thread ----
    const f32x4* enc4 = (const f32x4*)enc + (size_t)b * N_SZ * ROW4;
    f32x4*       out4 = (f32x4*)out + ((size_t)b * L_SZ + l0) * ROW4;
    const int c4 = tid & (ROW4 - 1);
    const int rh = tid >> 7;             // 0/1: two rows per pass
    #pragma unroll
    for (int rr = 0; rr < 4; ++rr) {
        const int r = rr * 2 + rh;
        const int p = pl[r];             // LDS broadcast, wave-uniform
        f32x4 v = (f32x4)(0.0f);
        if (p >= 0) v = enc4[p * ROW4 + c4];
        out4[r * ROW4 + c4] = v;
    }
}

extern "C" void kernel_launch(void* const* d_in, const int* in_sizes, int n_in,
                              void* d_out, int out_size, void* d_ws, size_t ws_size,
                              hipStream_t stream) {
    const float* enc = (const float*)d_in[0];   // (16, 512, 512) fp32
    const float* ld  = (const float*)d_in[1];   // (16, 512, 1)  fp32
    float* out       = (float*)d_out;           // (16, 2048, 512) fp32

    lenreg_fused_kernel<<<NBLOCKS, THREADS, 0, stream>>>(enc, ld, out);
}